// Round 14
// baseline (347.902 us; speedup 1.0000x reference)
//
#include <hip/hip_runtime.h>

#define SLEN 200
#define NB   2048

typedef short  bf8s   __attribute__((ext_vector_type(8)));
typedef __bf16 bf16x8 __attribute__((ext_vector_type(8)));
typedef float  f4     __attribute__((ext_vector_type(4)));

__device__ __forceinline__ short fb1(float x){ __bf16 b=(__bf16)x; return __builtin_bit_cast(short,b); }
__device__ __forceinline__ float b2f(unsigned short b){
  return __builtin_bit_cast(float, ((unsigned int)b)<<16);
}
__device__ __forceinline__ float ldf(const void* p, long i, bool bf){
  return bf ? b2f(((const unsigned short*)p)[i]) : ((const float*)p)[i];
}
__device__ __forceinline__ bf8s loadfrag(const void* p, long i, bool bf){
  bf8s r;
  if (bf) {
    r = *(const bf8s*)((const unsigned short*)p + i);
  } else {
    const float* q = (const float*)p + i;
#pragma unroll
    for (int k=0;k<8;k++) r[k] = fb1(q[k]);
  }
  return r;
}
__device__ __forceinline__ float rcp_(float x){ return __builtin_amdgcn_rcpf(x); }
__device__ __forceinline__ float sigm(float x){ return rcp_(1.f + __expf(-x)); }
__device__ __forceinline__ float tanh_(float x){ return 1.f - 2.f*rcp_(1.f + __expf(2.f*x)); }
__device__ __forceinline__ f4 MF(bf8s a, bf8s b, f4 c){
  return __builtin_amdgcn_mfma_f32_16x16x32_bf16(
    __builtin_bit_cast(bf16x8,a), __builtin_bit_cast(bf16x8,b), c, 0,0,0);
}
__device__ __forceinline__ void sync_lds(){
  asm volatile("s_waitcnt lgkmcnt(0)" ::: "memory");
  __builtin_amdgcn_s_barrier();
  __builtin_amdgcn_sched_barrier(0);
}
// MFMA 16x16x32 layouts (validated r3-r13): A/B: nonK=lane&15, k=8*(lane>>4)+j;
// D: col=lane&15, row=4*(lane>>4)+reg.
// 4-row mapping (this round): batch b at A/D-row 4b; D-reg i=0 of lane-quad q
// is batch q -> exactly 1 activation set per lane; A-rows 4b+1..3 stay zero
// (h) or duplicate (x/hidden global loads) -> junk D rows, never read.

// ---------------- K0: dtype detect + counting sort (merged, parallel prefix) ----------------
__global__ __launch_bounds__(256)
void k0_prep(const unsigned int* wds, int nw, const int* lengths, int* flag, int* perm){
  __shared__ int hist[256];
  __shared__ int base[256];
  __shared__ int cnt[256];
  __shared__ int wsum[4];
  const int tid = threadIdx.x;
  int c = 0;
  for (int i=tid;i<nw;i+=256){
    unsigned e = (wds[i] >> 7) & 0xFFu;
    c += (e >= 96u && e <= 160u) ? 1 : 0;
  }
  cnt[tid]=c; hist[tid]=0;
  __syncthreads();
  for (int s=128;s>0;s>>=1){
    if (tid<s) cnt[tid]+=cnt[tid+s];
    __syncthreads();
  }
  if (tid==0) flag[0] = (cnt[0]*2 > nw) ? 1 : 0;
  for (int i=tid;i<NB;i+=256) atomicAdd(&hist[lengths[i]&255],1);
  __syncthreads();
  {
    const int lane=tid&63, w=tid>>6;
    int v = hist[tid];
    int sum = v;
#pragma unroll
    for (int d=1; d<64; d<<=1){
      int o = __shfl_up(sum, d);
      if (lane >= d) sum += o;
    }
    if (lane==63) wsum[w]=sum;
    __syncthreads();
    int woff=0;
#pragma unroll
    for (int k=0;k<4;++k) if (k<w) woff+=wsum[k];
    base[tid] = woff + sum - v;
  }
  __syncthreads();
  for (int i=tid;i<NB;i+=256){
    int l=lengths[i]&255;
    int p=atomicAdd(&base[l],1);
    perm[p]=i;
  }
}

// ---------------- Fused DIEN: 4 rows/block, 512 blocks, multi-block/CU ----------------
__global__ __launch_bounds__(256,3)
void fused(const void* behavior, const void* target, const int* lengths,
           const void* Wih, const void* Whh, const void* bih, const void* bhh,
           const void* A1, const void* b1, const void* A2,
           const void* Wr, const void* br, const void* Wz, const void* bz,
           const void* Wn, const void* bn,
           const int* perm, const int* flag,
           unsigned short* hidden, float* out){
  const bool bf = flag[0]!=0;
  const int tid=threadIdx.x, lane=tid&63, w=tid>>6, l15=lane&15, q=lane>>4;
  // length-matched pairing: blocks j and j+256 take adjacent 4-row halves of
  // the same sorted 8-row window -> co-resident blocks have similar maxlen.
  const int g0 = (blockIdx.x & 255)*8 + (blockIdx.x >> 8)*4;
  const int xb = l15>>2;                      // A-row -> batch (dup for junk rows)

  __shared__ alignas(16) unsigned short h_lds[2][16][72];
  __shared__ alignas(16) unsigned short h_hist[16][4][72];   // 16-step ring
  __shared__ alignas(16) unsigned short rh_lds[16][72];
  __shared__ float att_l[4][200];
  __shared__ float score_s[4][208];
  __shared__ float ct_s[4][64];
  __shared__ alignas(16) unsigned short tg_s[4][72];
  __shared__ float a2_s[64];
  __shared__ int rows4[4], lens4[4];

  if (tid<4){ int r=perm[g0+tid]; rows4[tid]=r; lens4[tid]=lengths[r]; }
  for (int i=tid;i<2*16*72;i+=256) ((unsigned short*)h_lds)[i]=0;
  for (int i=tid;i<16*72;i+=256)   ((unsigned short*)rh_lds)[i]=0;
  __syncthreads();

  int maxlen=1;
#pragma unroll
  for (int i=0;i<4;++i) maxlen = max(maxlen, lens4[i]);
  const int ml1 = maxlen-1;
  const int jc = w*16 + l15;

  const unsigned short* bp=(const unsigned short*)behavior;
  const float*          fp=(const float*)behavior;

  auto dump_window = [&](int tbase){
    int dt = tid>>5, row=(tid>>3)&3, cs=(tid&7)*8;
    int t = tbase+dt;
    if (t < lens4[row]){
      uint4 v0 = *(const uint4*)&h_hist[t&15][row][cs];
      long o = ((long)rows4[row]*SLEN + t)*64 + cs;
      *(uint4*)&hidden[o] = v0;
    }
  };

  // ================= Phase 1: interest-extraction GRU =================
  {
    bf8s wif[3][2], whf[3][2];
#pragma unroll
    for (int G=0;G<3;++G)
#pragma unroll
      for (int kf=0;kf<2;++kf){
        long off = (long)(G*64+jc)*64 + kf*32 + q*8;
        wif[G][kf] = loadfrag(Wih, off, bf);
        whf[G][kf] = loadfrag(Whh, off, bf);
      }
    const float Br  = ldf(bih,jc,bf)+ldf(bhh,jc,bf);
    const float Bz  = ldf(bih,64+jc,bf)+ldf(bhh,64+jc,bf);
    const float Bin = ldf(bih,128+jc,bf);
    const float Bhn = ldf(bhh,128+jc,bf);
    const int LnQ = lens4[q];
    float hreg = 0.f;

    const long xbase = (long)rows4[xb]*(SLEN*64) + q*8;
    bf8s xC0,xC1,xN0,xN1;
    f4 c0,c1,c2,c3, n0,n1,n2,n3;
    {
      long o0=xbase, o1=xbase+(long)min(1,ml1)*64;
      if (bf){
        xC0=*(const bf8s*)(bp+o0); xC1=*(const bf8s*)(bp+o0+32);
        xN0=*(const bf8s*)(bp+o1); xN1=*(const bf8s*)(bp+o1+32);
      } else {
        c0=*(const f4*)(fp+o0); c1=*(const f4*)(fp+o0+4); c2=*(const f4*)(fp+o0+32); c3=*(const f4*)(fp+o0+36);
        n0=*(const f4*)(fp+o1); n1=*(const f4*)(fp+o1+4); n2=*(const f4*)(fp+o1+32); n3=*(const f4*)(fp+o1+36);
      }
    }

    for (int t=0;t<maxlen;++t){
      if ((t&7)==0 && t>=8) dump_window(t-8);
      long po = xbase + (long)min(t+2,ml1)*64;
      bf8s pN0,pN1; f4 p0,p1,p2,p3;
      if (bf){ pN0=*(const bf8s*)(bp+po); pN1=*(const bf8s*)(bp+po+32); }
      else   { p0=*(const f4*)(fp+po); p1=*(const f4*)(fp+po+4); p2=*(const f4*)(fp+po+32); p3=*(const f4*)(fp+po+36); }

      bf8s ha0 = *(const bf8s*)&h_lds[t&1][l15][q*8];
      bf8s ha1 = *(const bf8s*)&h_lds[t&1][l15][32+q*8];
      bf8s xa0, xa1;
      if (bf){ xa0=xC0; xa1=xC1; }
      else {
#pragma unroll
        for (int j=0;j<4;++j){
          xa0[j]=fb1(c0[j]); xa0[4+j]=fb1(c1[j]);
          xa1[j]=fb1(c2[j]); xa1[4+j]=fb1(c3[j]);
        }
      }

      f4 Tr  = {Br,Br,Br,Br};
      f4 Tz  = {Bz,Bz,Bz,Bz};
      f4 Txn = {Bin,Bin,Bin,Bin};
      f4 Thn = {Bhn,Bhn,Bhn,Bhn};
      Tr =MF(xa0,wif[0][0],Tr );  Tr =MF(xa1,wif[0][1],Tr );
      Tz =MF(xa0,wif[1][0],Tz );  Tz =MF(xa1,wif[1][1],Tz );
      Txn=MF(xa0,wif[2][0],Txn);  Txn=MF(xa1,wif[2][1],Txn);
      Tr =MF(ha0,whf[0][0],Tr );  Tr =MF(ha1,whf[0][1],Tr );
      Tz =MF(ha0,whf[1][0],Tz );  Tz =MF(ha1,whf[1][1],Tz );
      Thn=MF(ha0,whf[2][0],Thn);  Thn=MF(ha1,whf[2][1],Thn);

      const int nb_=(t+1)&1;
      {
        float rg = sigm(Tr[0]);
        float zg = sigm(Tz[0]);
        float ng = tanh_(Txn[0] + rg*Thn[0]);
        float hnew = (1.f-zg)*ng + zg*hreg;
        float hv = (t < LnQ) ? hnew : hreg;
        hreg = hv;
        unsigned short hb16 = (unsigned short)fb1(hv);
        h_lds[nb_][4*q][jc] = hb16;
        h_hist[t&15][q][jc] = hb16;
      }
      if (bf){ xC0=xN0; xC1=xN1; xN0=pN0; xN1=pN1; }
      else   { c0=n0;c1=n1;c2=n2;c3=n3; n0=p0;n1=p1;n2=p2;n3=p3; }
      sync_lds();
    }
    dump_window((maxlen-1)&~7);
    asm volatile("s_waitcnt vmcnt(0)" ::: "memory");
  }
  __syncthreads();   // hidden complete & visible

  // ================= Phase 2: attention MLP + masked softmax (1 row/wave) ========
  for (int i=tid;i<4*64;i+=256){
    int r=i>>6, c2=i&63;
    tg_s[r][c2] = (unsigned short)fb1(ldf(target,(long)rows4[r]*64 + c2, bf));
  }
  if (tid<64) a2_s[tid]=ldf(A2,tid,bf);
  __syncthreads();

  {
    // ct via MFMA: D(a = w*16+4q+i, batch = l15) = A1h2 @ tg^T
    {
      bf8s a1c0 = loadfrag(A1,(long)(w*16+l15)*128 + 64 + q*8, bf);
      bf8s a1c1 = loadfrag(A1,(long)(w*16+l15)*128 + 96 + q*8, bf);
      bf8s tgf0 = *(const bf8s*)&tg_s[l15&3][q*8];
      bf8s tgf1 = *(const bf8s*)&tg_s[l15&3][32+q*8];
      f4 Dct={0.f,0.f,0.f,0.f};
      Dct=MF(a1c0,tgf0,Dct);
      Dct=MF(a1c1,tgf1,Dct);
      if (l15<4){
#pragma unroll
        for (int i=0;i<4;++i)
          ct_s[l15][w*16+4*q+i] = Dct[i] + ldf(b1,w*16+4*q+i,bf);
      }
    }
    bf8s a1f[4][2];
#pragma unroll
    for (int nt=0;nt<4;++nt)
#pragma unroll
      for (int kf=0;kf<2;++kf)
        a1f[nt][kf] = loadfrag(A1,(long)(nt*16+l15)*128 + kf*32 + q*8, bf);
    __syncthreads();   // ct_s complete

    const int r = w, lenr = lens4[r];
    int mtr = (lenr+15)>>4; if (mtr>13) mtr=13;
    for (int mt=0; mt<mtr; ++mt){
      const unsigned short* hp = &hidden[((long)rows4[r]*SLEN + mt*16+l15)*64 + q*8];
      bf8s h0 = *(const bf8s*)hp;
      bf8s h1 = *(const bf8s*)(hp+32);
      f4 acc[4];
#pragma unroll
      for (int nt=0;nt<4;++nt){
        f4 a={0.f,0.f,0.f,0.f};
        a=MF(h0,a1f[nt][0],a); a=MF(h1,a1f[nt][1],a); acc[nt]=a;
      }
#pragma unroll
      for (int i=0;i<4;++i){
        float s=0.f;
#pragma unroll
        for (int nt=0;nt<4;++nt){
          int au = nt*16 + l15;
          s += fmaxf(acc[nt][i]+ct_s[r][au],0.f)*a2_s[au];
        }
#pragma unroll
        for (int d=1; d<16; d<<=1) s += __shfl_xor(s,d);
        if (l15==0) score_s[r][mt*16+4*q+i] = s;
      }
    }
    int t0=lane, t1=64+lane, t2=128+lane, t3=192+lane;
    float v0=(t0<lenr)?score_s[r][t0]:-3e38f;
    float v1=(t1<lenr)?score_s[r][t1]:-3e38f;
    float v2=(t2<lenr)?score_s[r][t2]:-3e38f;
    float v3=(t3<lenr)?score_s[r][t3]:-3e38f;
    float m = fmaxf(fmaxf(v0,v1),fmaxf(v2,v3));
#pragma unroll
    for (int d=32;d>0;d>>=1) m = fmaxf(m,__shfl_xor(m,d));
    float e0=(t0<lenr)?__expf(v0-m):0.f;
    float e1=(t1<lenr)?__expf(v1-m):0.f;
    float e2=(t2<lenr)?__expf(v2-m):0.f;
    float e3=(t3<lenr)?__expf(v3-m):0.f;
    float S = e0+e1+e2+e3;
#pragma unroll
    for (int d=32;d>0;d>>=1) S += __shfl_xor(S,d);
    float Si = rcp_(S);
    att_l[r][t0] = e0*Si;
    att_l[r][t1] = e1*Si;
    if (t2<200) att_l[r][t2] = e2*Si;
    if (t3<200) att_l[r][t3] = e3*Si;
  }
  __syncthreads();

  // ====== Phase 3: attentional GRU (direct global prefetch) ======
  for (int i=tid;i<2*16*72;i+=256) ((unsigned short*)h_lds)[i]=0;

  bf8s wrf[2][2], wzf[2][2], wnf[2][2];     // [0]=hi part, [1]=h part
#pragma unroll
  for (int hh=0;hh<2;++hh)
#pragma unroll
    for (int kf=0;kf<2;++kf){
      long off = (long)jc*128 + hh*64 + kf*32 + q*8;
      wrf[hh][kf]=loadfrag(Wr,off,bf);
      wzf[hh][kf]=loadfrag(Wz,off,bf);
      wnf[hh][kf]=loadfrag(Wn,off,bf);
    }
  const float Brv=ldf(br,jc,bf), Bzv=ldf(bz,jc,bf), Bnv=ldf(bn,jc,bf);

  float h3 = 0.f;
  const long hbase = (long)rows4[xb]*(SLEN*64) + q*8;
  bf8s hb00,hb01,hb10,hb11;
  {
    long o1 = hbase + (long)min(1,ml1)*64;
    hb00=*(const bf8s*)(hidden+hbase); hb01=*(const bf8s*)(hidden+hbase+32);
    hb10=*(const bf8s*)(hidden+o1);    hb11=*(const bf8s*)(hidden+o1+32);
  }
  __syncthreads();   // h_lds zero visible

  for (int t=0;t<maxlen;++t){
    long po = hbase + (long)min(t+2,ml1)*64;
    bf8s pN0 = *(const bf8s*)(hidden+po);
    bf8s pN1 = *(const bf8s*)(hidden+po+32);

    bf8s ha0=*(const bf8s*)&h_lds[t&1][l15][q*8];
    bf8s ha1=*(const bf8s*)&h_lds[t&1][l15][32+q*8];

    f4 Tr = {Brv,Brv,Brv,Brv};
    f4 Tz = {Bzv,Bzv,Bzv,Bzv};
    f4 Tn = {Bnv,Bnv,Bnv,Bnv};
    Tr=MF(hb00,wrf[0][0],Tr); Tr=MF(hb01,wrf[0][1],Tr);
    Tz=MF(hb00,wzf[0][0],Tz); Tz=MF(hb01,wzf[0][1],Tz);
    Tn=MF(hb00,wnf[0][0],Tn); Tn=MF(hb01,wnf[0][1],Tn);
    Tr=MF(ha0, wrf[1][0],Tr); Tr=MF(ha1, wrf[1][1],Tr);
    Tz=MF(ha0, wzf[1][0],Tz); Tz=MF(ha1, wzf[1][1],Tz);

    float zs, hs;
    {
      float rg = sigm(Tr[0]);
      float ai = att_l[q][t];
      zs = sigm(Tz[0]) * ai;
      hs = h3;
      rh_lds[4*q][jc] = (unsigned short)fb1(rg*hs);
    }
    sync_lds();                            // rh visible

    bf8s ra0 = *(const bf8s*)&rh_lds[l15][q*8];
    bf8s ra1 = *(const bf8s*)&rh_lds[l15][32+q*8];
    Tn=MF(ra0,wnf[1][0],Tn); Tn=MF(ra1,wnf[1][1],Tn);

    const int nb_=(t+1)&1;
    {
      float ng = tanh_(Tn[0]);
      float hnew = (zs==0.f) ? hs : hs + zs*(ng - hs);
      h3 = hnew;
      h_lds[nb_][4*q][jc] = (unsigned short)fb1(hnew);
    }
    hb00=hb10; hb01=hb11; hb10=pN0; hb11=pN1;
    sync_lds();                            // h visible
  }
  out[(long)rows4[q]*64 + jc] = h3;
}

extern "C" void kernel_launch(void* const* d_in, const int* in_sizes, int n_in,
                              void* d_out, int out_size, void* d_ws, size_t ws_size,
                              hipStream_t stream) {
  const void* behavior = d_in[0];
  const void* target   = d_in[1];
  const int*  lengths  = (const int*)d_in[2];
  const void* Wih = d_in[3];
  const void* Whh = d_in[4];
  const void* bih = d_in[5];
  const void* bhh = d_in[6];
  const void* A1  = d_in[7];
  const void* b1  = d_in[8];
  const void* A2  = d_in[9];
  const void* Wr  = d_in[10];
  const void* br  = d_in[11];
  const void* Wz  = d_in[12];
  const void* bz  = d_in[13];
  const void* Wn  = d_in[14];
  const void* bn  = d_in[15];

  int* flag = (int*)d_ws;
  unsigned short* hidden = (unsigned short*)((char*)d_ws + 256);
  int* perm = (int*)((char*)d_ws + 256 + (size_t)NB*SLEN*64*2);
  size_t needed = 256 + (size_t)NB*SLEN*64*2 + (size_t)NB*4;
  if (ws_size < needed) return;

  k0_prep<<<1, 256, 0, stream>>>((const unsigned int*)behavior, 4096, lengths, flag, perm);
  fused<<<512, 256, 0, stream>>>(behavior, target, lengths,
                                 Wih, Whh, bih, bhh, A1, b1, A2,
                                 Wr, br, Wz, bz, Wn, bn,
                                 perm, flag, hidden, (float*)d_out);
}

// Round 15
// 264.370 us; speedup vs baseline: 1.3160x; 1.3160x over previous
//
#include <hip/hip_runtime.h>

#define SLEN 200
#define NB   2048

typedef short  bf8s   __attribute__((ext_vector_type(8)));
typedef __bf16 bf16x8 __attribute__((ext_vector_type(8)));
typedef float  f4     __attribute__((ext_vector_type(4)));

__device__ __forceinline__ short fb1(float x){ __bf16 b=(__bf16)x; return __builtin_bit_cast(short,b); }
__device__ __forceinline__ float b2f(unsigned short b){
  return __builtin_bit_cast(float, ((unsigned int)b)<<16);
}
__device__ __forceinline__ float ldf(const void* p, long i, bool bf){
  return bf ? b2f(((const unsigned short*)p)[i]) : ((const float*)p)[i];
}
__device__ __forceinline__ bf8s loadfrag(const void* p, long i, bool bf){
  bf8s r;
  if (bf) {
    r = *(const bf8s*)((const unsigned short*)p + i);
  } else {
    const float* q = (const float*)p + i;
#pragma unroll
    for (int k=0;k<8;k++) r[k] = fb1(q[k]);
  }
  return r;
}
__device__ __forceinline__ float rcp_(float x){ return __builtin_amdgcn_rcpf(x); }
__device__ __forceinline__ float sigm(float x){ return rcp_(1.f + __expf(-x)); }
__device__ __forceinline__ float tanh_(float x){ return 1.f - 2.f*rcp_(1.f + __expf(2.f*x)); }
__device__ __forceinline__ f4 MF(bf8s a, bf8s b, f4 c){
  return __builtin_amdgcn_mfma_f32_16x16x32_bf16(
    __builtin_bit_cast(bf16x8,a), __builtin_bit_cast(bf16x8,b), c, 0,0,0);
}
__device__ __forceinline__ void sync_lds(){
  asm volatile("s_waitcnt lgkmcnt(0)" ::: "memory");
  __builtin_amdgcn_s_barrier();
  __builtin_amdgcn_sched_barrier(0);
}
// MFMA 16x16x32 layouts (validated r3-r14): A/B: nonK=lane&15, k=8*(lane>>4)+j;
// D: col=lane&15, row=4*(lane>>4)+reg.
// Rowmap (r13-validated): batch b at A/D-row 4*(b>>1)+(b&1) -> D-regs i in {0,1}
// of lane-quad q map to batch 2q+i -> 2 activation sets per lane.
// Swapped-r pi-permute (r8-validated): pi(tt,i | lane) = 32*(tt>>1)+8q+4*(tt&1)+i.

// ---------------- K0: dtype detect + counting sort (merged, parallel prefix) ----------------
__global__ __launch_bounds__(256)
void k0_prep(const unsigned int* wds, int nw, const int* lengths, int* flag, int* perm){
  __shared__ int hist[256];
  __shared__ int base[256];
  __shared__ int cnt[256];
  __shared__ int wsum[4];
  const int tid = threadIdx.x;
  int c = 0;
  for (int i=tid;i<nw;i+=256){
    unsigned e = (wds[i] >> 7) & 0xFFu;
    c += (e >= 96u && e <= 160u) ? 1 : 0;
  }
  cnt[tid]=c; hist[tid]=0;
  __syncthreads();
  for (int s=128;s>0;s>>=1){
    if (tid<s) cnt[tid]+=cnt[tid+s];
    __syncthreads();
  }
  if (tid==0) flag[0] = (cnt[0]*2 > nw) ? 1 : 0;
  for (int i=tid;i<NB;i+=256) atomicAdd(&hist[lengths[i]&255],1);
  __syncthreads();
  {
    const int lane=tid&63, w=tid>>6;
    int v = hist[tid];
    int sum = v;
#pragma unroll
    for (int d=1; d<64; d<<=1){
      int o = __shfl_up(sum, d);
      if (lane >= d) sum += o;
    }
    if (lane==63) wsum[w]=sum;
    __syncthreads();
    int woff=0;
#pragma unroll
    for (int k=0;k<4;++k) if (k<w) woff+=wsum[k];
    base[tid] = woff + sum - v;
  }
  __syncthreads();
  for (int i=tid;i<NB;i+=256){
    int l=lengths[i]&255;
    int p=atomicAdd(&base[l],1);
    perm[p]=i;
  }
}

// ---------------- Fused DIEN (r13 structure; ph3 = 1-barrier swapped-r) ----------------
__global__ __launch_bounds__(256,1)
void fused(const void* behavior, const void* target, const int* lengths,
           const void* Wih, const void* Whh, const void* bih, const void* bhh,
           const void* A1, const void* b1, const void* A2,
           const void* Wr, const void* br, const void* Wz, const void* bz,
           const void* Wn, const void* bn,
           const int* perm, const int* flag,
           unsigned short* hidden, float* out){
  const bool bf = flag[0]!=0;
  const int tid=threadIdx.x, lane=tid&63, w=tid>>6, l15=lane&15, q=lane>>4;
  const int g0 = blockIdx.x*8;
  const int xrow = ((l15>>2)<<1)|(l15&1);     // A-row -> batch (rowmap inverse, junk rows dup)

  __shared__ alignas(16) unsigned short x_s[2][40][8][72];   // staged x chunks (ph1)
  __shared__ alignas(16) unsigned short h_lds[2][16][72];
  __shared__ alignas(16) unsigned short h_hist[16][8][72];   // 16-step ring, batch-indexed
  __shared__ alignas(16) unsigned short rh_lds[16][72];      // used by ph1 zero only
  __shared__ float att_l[8][200];
  __shared__ float score_s[8][208];
  __shared__ float ct_s[8][64];
  __shared__ alignas(16) unsigned short tg_s[8][72];
  __shared__ float a2_s[64];
  __shared__ int rows8[8], lens8[8];

  if (tid<8){ int r=perm[g0+tid]; rows8[tid]=r; lens8[tid]=lengths[r]; }
  for (int i=tid;i<2*16*72;i+=256) ((unsigned short*)h_lds)[i]=0;
  for (int i=tid;i<16*72;i+=256)   ((unsigned short*)rh_lds)[i]=0;
  __syncthreads();

  int maxlen=1;
#pragma unroll
  for (int i=0;i<8;++i) maxlen = max(maxlen, lens8[i]);
  const int ml1 = maxlen-1;
  const int jc = w*16 + l15;

  const unsigned short* bp=(const unsigned short*)behavior;
  const float*          fp=(const float*)behavior;

  uint4 xr[10];                         // in-flight staging registers
  auto issue_g = [&](const unsigned short* src, int t0){
#pragma unroll
    for (int it=0; it<10; ++it){
      int i=it*256+tid, row=i/320, k=i-row*320;
      int t=min(t0+(k>>3), ml1), d0=(k&7)*8;
      xr[it] = *(const uint4*)(src + (long)rows8[row]*(SLEN*64) + t*64 + d0);
    }
  };
  auto write_s = [&](int b_){
#pragma unroll
    for (int it=0; it<10; ++it){
      int i=it*256+tid, row=i/320, k=i-row*320;
      *(uint4*)&x_s[b_][k>>3][row][(k&7)*8] = xr[it];
    }
  };
  auto f32_stage = [&](int b_, int t0){
#pragma unroll
    for (int it=0; it<10; ++it){
      int i=it*256+tid, row=i/320, k=i-row*320;
      int t=min(t0+(k>>3), ml1), d0=(k&7)*8;
      const float* s = fp + (long)rows8[row]*(SLEN*64) + t*64 + d0;
      f4 a=*(const f4*)s, b2=*(const f4*)(s+4);
      bf8s v;
#pragma unroll
      for (int j=0;j<4;++j){ v[j]=fb1(a[j]); v[4+j]=fb1(b2[j]); }
      *(bf8s*)&x_s[b_][k>>3][row][d0] = v;
    }
  };
  auto dump_window = [&](int tbase){
    int dt = tid>>5, row=(tid>>2)&7, cs=(tid&3)*16;
    int t = tbase+dt;
    if (t < lens8[row]){
      uint4 v0 = *(const uint4*)&h_hist[t&15][row][cs];
      uint4 v1 = *(const uint4*)&h_hist[t&15][row][cs+8];
      long o = ((long)rows8[row]*SLEN + t)*64 + cs;
      *(uint4*)&hidden[o]   = v0;
      *(uint4*)&hidden[o+8] = v1;
    }
  };

  // ================= Phase 1: interest-extraction GRU (r13 verbatim) =================
  {
    bf8s wif[3][2], whf[3][2];
#pragma unroll
    for (int G=0;G<3;++G)
#pragma unroll
      for (int kf=0;kf<2;++kf){
        long off = (long)(G*64+jc)*64 + kf*32 + q*8;
        wif[G][kf] = loadfrag(Wih, off, bf);
        whf[G][kf] = loadfrag(Whh, off, bf);
      }
    const float Br  = ldf(bih,jc,bf)+ldf(bhh,jc,bf);
    const float Bz  = ldf(bih,64+jc,bf)+ldf(bhh,64+jc,bf);
    const float Bin = ldf(bih,128+jc,bf);
    const float Bhn = ldf(bhh,128+jc,bf);
    int Ln2[2];
#pragma unroll
    for (int i=0;i<2;++i) Ln2[i] = lens8[2*q+i];
    float hreg[2]={0.f,0.f};

    if (bf){ issue_g(bp,0); write_s(0); if (maxlen>40) issue_g(bp,40); }
    else   { f32_stage(0,0); }
    __syncthreads();

    int c=0;
    for (int t0=0; t0<maxlen; t0+=40, ++c){
      const int tend = min(t0+40, maxlen);
      for (int t=t0; t<tend; ++t){
        if ((t&7)==0 && t>=8) dump_window(t-8);
        const int tc = t-t0;
        bf8s xa0 = *(const bf8s*)&x_s[c&1][tc][xrow][q*8];
        bf8s xa1 = *(const bf8s*)&x_s[c&1][tc][xrow][32+q*8];
        bf8s ha0 = *(const bf8s*)&h_lds[t&1][l15][q*8];
        bf8s ha1 = *(const bf8s*)&h_lds[t&1][l15][32+q*8];

        f4 Tr  = {Br,Br,Br,Br};
        f4 Tz  = {Bz,Bz,Bz,Bz};
        f4 Txn = {Bin,Bin,Bin,Bin};
        f4 Thn = {Bhn,Bhn,Bhn,Bhn};
        Tr =MF(xa0,wif[0][0],Tr );  Tr =MF(xa1,wif[0][1],Tr );
        Tz =MF(xa0,wif[1][0],Tz );  Tz =MF(xa1,wif[1][1],Tz );
        Txn=MF(xa0,wif[2][0],Txn);  Txn=MF(xa1,wif[2][1],Txn);
        Tr =MF(ha0,whf[0][0],Tr );  Tr =MF(ha1,whf[0][1],Tr );
        Tz =MF(ha0,whf[1][0],Tz );  Tz =MF(ha1,whf[1][1],Tz );
        Thn=MF(ha0,whf[2][0],Thn); Thn=MF(ha1,whf[2][1],Thn);

        const int nb_=(t+1)&1;
#pragma unroll
        for (int i=0;i<2;++i){
          const int ar = 4*q+i;          // D-row / A-row (rowmap space)
          const int b_ = 2*q+i;          // batch slot
          float rg = sigm(Tr[i]);
          float zg = sigm(Tz[i]);
          float ng = tanh_(Txn[i] + rg*Thn[i]);
          float hold = hreg[i];
          float hnew = (1.f-zg)*ng + zg*hold;
          float hv = (t < Ln2[i]) ? hnew : hold;
          hreg[i] = hv;
          unsigned short hb16 = (unsigned short)fb1(hv);
          h_lds[nb_][ar][jc] = hb16;
          h_hist[t&15][b_][jc] = hb16;
        }
        sync_lds();
      }
      if (t0+40 < maxlen){
        if (bf){ write_s((c+1)&1); if (t0+80 < maxlen) issue_g(bp, t0+80); }
        else   { f32_stage((c+1)&1, t0+40); }
        sync_lds();
      }
    }
    dump_window((maxlen-1)&~7);
    asm volatile("s_waitcnt vmcnt(0)" ::: "memory");
  }
  __syncthreads();   // hidden complete & visible

  // ================= Phase 2: attention MLP + masked softmax (r13 verbatim) ==========
  for (int i=tid;i<8*64;i+=256){
    int r=i>>6, c2=i&63;
    tg_s[r][c2] = (unsigned short)fb1(ldf(target,(long)rows8[r]*64 + c2, bf));
  }
  if (tid<64) a2_s[tid]=ldf(A2,tid,bf);
  __syncthreads();

  {
    {
      bf8s a1c0 = loadfrag(A1,(long)(w*16+l15)*128 + 64 + q*8, bf);
      bf8s a1c1 = loadfrag(A1,(long)(w*16+l15)*128 + 96 + q*8, bf);
      bf8s tgf0 = *(const bf8s*)&tg_s[l15&7][q*8];
      bf8s tgf1 = *(const bf8s*)&tg_s[l15&7][32+q*8];
      f4 Dct={0.f,0.f,0.f,0.f};
      Dct=MF(a1c0,tgf0,Dct);
      Dct=MF(a1c1,tgf1,Dct);
      if (l15<8){
#pragma unroll
        for (int i=0;i<4;++i)
          ct_s[l15][w*16+4*q+i] = Dct[i] + ldf(b1,w*16+4*q+i,bf);
      }
    }
    bf8s a1f[4][2];
#pragma unroll
    for (int nt=0;nt<4;++nt)
#pragma unroll
      for (int kf=0;kf<2;++kf)
        a1f[nt][kf] = loadfrag(A1,(long)(nt*16+l15)*128 + kf*32 + q*8, bf);
    __syncthreads();

#pragma unroll
    for (int rr=0;rr<2;++rr){
      int r = 2*w+rr, lenr = lens8[r];
      int mtr = (lenr+15)>>4; if (mtr>13) mtr=13;
      for (int mt=0; mt<mtr; ++mt){
        const unsigned short* hp = &hidden[((long)rows8[r]*SLEN + mt*16+l15)*64 + q*8];
        bf8s h0 = *(const bf8s*)hp;
        bf8s h1 = *(const bf8s*)(hp+32);
        f4 acc[4];
#pragma unroll
        for (int nt=0;nt<4;++nt){
          f4 a={0.f,0.f,0.f,0.f};
          a=MF(h0,a1f[nt][0],a); a=MF(h1,a1f[nt][1],a); acc[nt]=a;
        }
#pragma unroll
        for (int i=0;i<4;++i){
          float s=0.f;
#pragma unroll
          for (int nt=0;nt<4;++nt){
            int au = nt*16 + l15;
            s += fmaxf(acc[nt][i]+ct_s[r][au],0.f)*a2_s[au];
          }
#pragma unroll
          for (int d=1; d<16; d<<=1) s += __shfl_xor(s,d);
          if (l15==0) score_s[r][mt*16+4*q+i] = s;
        }
      }
      int t0=lane, t1=64+lane, t2=128+lane, t3=192+lane;
      float v0=(t0<lenr)?score_s[r][t0]:-3e38f;
      float v1=(t1<lenr)?score_s[r][t1]:-3e38f;
      float v2=(t2<lenr)?score_s[r][t2]:-3e38f;
      float v3=(t3<lenr)?score_s[r][t3]:-3e38f;
      float m = fmaxf(fmaxf(v0,v1),fmaxf(v2,v3));
#pragma unroll
      for (int d=32;d>0;d>>=1) m = fmaxf(m,__shfl_xor(m,d));
      float e0=(t0<lenr)?__expf(v0-m):0.f;
      float e1=(t1<lenr)?__expf(v1-m):0.f;
      float e2=(t2<lenr)?__expf(v2-m):0.f;
      float e3=(t3<lenr)?__expf(v3-m):0.f;
      float S = e0+e1+e2+e3;
#pragma unroll
      for (int d=32;d>0;d>>=1) S += __shfl_xor(S,d);
      float Si = rcp_(S);
      att_l[r][t0] = e0*Si;
      att_l[r][t1] = e1*Si;
      if (t2<200) att_l[r][t2] = e2*Si;
      if (t3<200) att_l[r][t3] = e3*Si;
    }
  }
  __syncthreads();

  // ====== Phase 3: attentional GRU — swapped-r, ONE barrier/step ======
  for (int i=tid;i<2*16*72;i+=256) ((unsigned short*)h_lds)[i]=0;

  // pi-permuted Wr A-frags (r8-validated): row(tt,i|lane) = 32*(tt>>1)+8q+4*(tt&1)+i
  bf8s wrp[4][4];           // [tt][kf]: kf0/1 = hi cols 0-63, kf2/3 = h cols 64-127
  f4 brp[4];
#pragma unroll
  for (int tt=0;tt<4;++tt){
    int prow_l = 32*(tt>>1) + 8*(l15>>2) + 4*(tt&1) + (l15&3);
#pragma unroll
    for (int kf=0;kf<4;++kf){
      bf8s v;
#pragma unroll
      for (int j=0;j<8;++j)
        v[j] = fb1(ldf(Wr, (long)prow_l*128 + kf*32 + 8*q + j, bf));
      wrp[tt][kf]=v;
    }
#pragma unroll
    for (int i=0;i<4;++i){
      int pr = 32*(tt>>1) + 8*q + 4*(tt&1) + i;
      brp[tt][i] = ldf(br, pr, bf);
    }
  }
  bf8s wzf[2][2], wnf[2][2];     // [0]=hi part, [1]=h/rh part (B-frags, col jc)
#pragma unroll
  for (int hh=0;hh<2;++hh)
#pragma unroll
    for (int kf=0;kf<2;++kf){
      long off = (long)jc*128 + hh*64 + kf*32 + q*8;
      wzf[hh][kf]=loadfrag(Wz,off,bf);
      wnf[hh][kf]=loadfrag(Wn,off,bf);
    }
  const float Bzv=ldf(bz,jc,bf), Bnv=ldf(bn,jc,bf);

  float h3[2]={0.f,0.f};
  const long hbase = (long)rows8[xrow]*(SLEN*64) + q*8;
  bf8s hb00,hb01,hb10,hb11;
  {
    long o1 = hbase + (long)min(1,ml1)*64;
    hb00=*(const bf8s*)(hidden+hbase); hb01=*(const bf8s*)(hidden+hbase+32);
    hb10=*(const bf8s*)(hidden+o1);    hb11=*(const bf8s*)(hidden+o1+32);
  }
  __syncthreads();   // h_lds zero visible

  for (int t=0;t<maxlen;++t){
    long po = hbase + (long)min(t+2,ml1)*64;
    bf8s pN0 = *(const bf8s*)(hidden+po);
    bf8s pN1 = *(const bf8s*)(hidden+po+32);

    bf8s ha0=*(const bf8s*)&h_lds[t&1][l15][q*8];
    bf8s ha1=*(const bf8s*)&h_lds[t&1][l15][32+q*8];

    // swapped r-gate: D col = l15 (batch A-row space), rows = pi-cols
    f4 Dr0=brp[0], Dr1=brp[1], Dr2=brp[2], Dr3=brp[3];
    Dr0=MF(wrp[0][0],hb00,Dr0); Dr0=MF(wrp[0][1],hb01,Dr0);
    Dr0=MF(wrp[0][2],ha0,Dr0);  Dr0=MF(wrp[0][3],ha1,Dr0);
    Dr1=MF(wrp[1][0],hb00,Dr1); Dr1=MF(wrp[1][1],hb01,Dr1);
    Dr1=MF(wrp[1][2],ha0,Dr1);  Dr1=MF(wrp[1][3],ha1,Dr1);
    Dr2=MF(wrp[2][0],hb00,Dr2); Dr2=MF(wrp[2][1],hb01,Dr2);
    Dr2=MF(wrp[2][2],ha0,Dr2);  Dr2=MF(wrp[2][3],ha1,Dr2);
    Dr3=MF(wrp[3][0],hb00,Dr3); Dr3=MF(wrp[3][1],hb01,Dr3);
    Dr3=MF(wrp[3][2],ha0,Dr3);  Dr3=MF(wrp[3][3],ha1,Dr3);

    // z (normal orientation)
    f4 Tz = {Bzv,Bzv,Bzv,Bzv};
    Tz=MF(hb00,wzf[0][0],Tz); Tz=MF(hb01,wzf[0][1],Tz);
    Tz=MF(ha0, wzf[1][0],Tz); Tz=MF(ha1, wzf[1][1],Tz);

    // rh fragments in-lane (r8 mapping)
    float rgv0[4],rgv1[4],rgv2[4],rgv3[4];
#pragma unroll
    for (int i=0;i<4;++i){ rgv0[i]=sigm(Dr0[i]); rgv1[i]=sigm(Dr1[i]);
                           rgv2[i]=sigm(Dr2[i]); rgv3[i]=sigm(Dr3[i]); }
    bf8s rha0, rha1;
#pragma unroll
    for (int j=0;j<4;++j){
      rha0[j]   = fb1(rgv0[j] * b2f((unsigned short)ha0[j]));
      rha0[4+j] = fb1(rgv1[j] * b2f((unsigned short)ha0[4+j]));
      rha1[j]   = fb1(rgv2[j] * b2f((unsigned short)ha1[j]));
      rha1[4+j] = fb1(rgv3[j] * b2f((unsigned short)ha1[4+j]));
    }

    // n (normal orientation)
    f4 Tn = {Bnv,Bnv,Bnv,Bnv};
    Tn=MF(hb00,wnf[0][0],Tn); Tn=MF(hb01,wnf[0][1],Tn);
    Tn=MF(rha0,wnf[1][0],Tn); Tn=MF(rha1,wnf[1][1],Tn);

    const int nb_=(t+1)&1;
#pragma unroll
    for (int i=0;i<2;++i){
      const int ar = 4*q+i;
      const int b_ = 2*q+i;
      float ai = att_l[b_][t];
      float zg = sigm(Tz[i]) * ai;
      float ng = tanh_(Tn[i]);
      float hold = h3[i];
      float hnew = (zg==0.f) ? hold : hold + zg*(ng - hold);
      h3[i] = hnew;
      h_lds[nb_][ar][jc] = (unsigned short)fb1(hnew);
    }
    hb00=hb10; hb01=hb11; hb10=pN0; hb11=pN1;
    sync_lds();                            // single barrier: h visible
  }
#pragma unroll
  for (int i=0;i<2;++i)
    out[(long)rows8[2*q+i]*64 + jc] = h3[i];
}

extern "C" void kernel_launch(void* const* d_in, const int* in_sizes, int n_in,
                              void* d_out, int out_size, void* d_ws, size_t ws_size,
                              hipStream_t stream) {
  const void* behavior = d_in[0];
  const void* target   = d_in[1];
  const int*  lengths  = (const int*)d_in[2];
  const void* Wih = d_in[3];
  const void* Whh = d_in[4];
  const void* bih = d_in[5];
  const void* bhh = d_in[6];
  const void* A1  = d_in[7];
  const void* b1  = d_in[8];
  const void* A2  = d_in[9];
  const void* Wr  = d_in[10];
  const void* br  = d_in[11];
  const void* Wz  = d_in[12];
  const void* bz  = d_in[13];
  const void* Wn  = d_in[14];
  const void* bn  = d_in[15];

  int* flag = (int*)d_ws;
  unsigned short* hidden = (unsigned short*)((char*)d_ws + 256);
  int* perm = (int*)((char*)d_ws + 256 + (size_t)NB*SLEN*64*2);
  size_t needed = 256 + (size_t)NB*SLEN*64*2 + (size_t)NB*4;
  if (ws_size < needed) return;

  k0_prep<<<1, 256, 0, stream>>>((const unsigned int*)behavior, 4096, lengths, flag, perm);
  fused<<<NB/8, 256, 0, stream>>>(behavior, target, lengths,
                                  Wih, Whh, bih, bhh, A1, b1, A2,
                                  Wr, br, Wz, bz, Wn, bn,
                                  perm, flag, hidden, (float*)d_out);
}

// Round 16
// 224.524 us; speedup vs baseline: 1.5495x; 1.1775x over previous
//
#include <hip/hip_runtime.h>

#define SLEN 200
#define NB   2048
#define CS   40          // staged chunk length (200 = 5 chunks)

typedef short  bf8s   __attribute__((ext_vector_type(8)));
typedef __bf16 bf16x8 __attribute__((ext_vector_type(8)));
typedef float  f4     __attribute__((ext_vector_type(4)));

__device__ __forceinline__ short fb1(float x){ __bf16 b=(__bf16)x; return __builtin_bit_cast(short,b); }
__device__ __forceinline__ float b2f(unsigned short b){
  return __builtin_bit_cast(float, ((unsigned int)b)<<16);
}
__device__ __forceinline__ float ldf(const void* p, long i, bool bf){
  return bf ? b2f(((const unsigned short*)p)[i]) : ((const float*)p)[i];
}
__device__ __forceinline__ bf8s loadfrag(const void* p, long i, bool bf){
  bf8s r;
  if (bf) {
    r = *(const bf8s*)((const unsigned short*)p + i);
  } else {
    const float* q = (const float*)p + i;
#pragma unroll
    for (int k=0;k<8;k++) r[k] = fb1(q[k]);
  }
  return r;
}
__device__ __forceinline__ float rcp_(float x){ return __builtin_amdgcn_rcpf(x); }
__device__ __forceinline__ float sigm(float x){ return rcp_(1.f + __expf(-x)); }
__device__ __forceinline__ float tanh_(float x){ return 1.f - 2.f*rcp_(1.f + __expf(2.f*x)); }
__device__ __forceinline__ f4 MF(bf8s a, bf8s b, f4 c){
  return __builtin_amdgcn_mfma_f32_16x16x32_bf16(
    __builtin_bit_cast(bf16x8,a), __builtin_bit_cast(bf16x8,b), c, 0,0,0);
}
// lgkm-drain + barrier; memory clobbers enforce LDS ordering but allow the
// compiler to schedule register-only work across the barrier (r16 change:
// no sched_barrier(0)).
__device__ __forceinline__ void sync_lds(){
  asm volatile("s_waitcnt lgkmcnt(0)" ::: "memory");
  __builtin_amdgcn_s_barrier();
  asm volatile("" ::: "memory");
}
// MFMA 16x16x32 layouts (validated r3-r15): A/B: nonK=lane&15, k=8*(lane>>4)+j;
// D: col=lane&15, row=4*(lane>>4)+reg.
// Rowmap (r13-validated): batch b at A/D-row 4*(b>>1)+(b&1) -> D-regs i in {0,1}
// of lane-quad q map to batch 2q+i -> 2 activation sets per lane.

// ---------------- K0: dtype detect + counting sort (merged, parallel prefix) ----------------
__global__ __launch_bounds__(256)
void k0_prep(const unsigned int* wds, int nw, const int* lengths, int* flag, int* perm){
  __shared__ int hist[256];
  __shared__ int base[256];
  __shared__ int cnt[256];
  __shared__ int wsum[4];
  const int tid = threadIdx.x;
  int c = 0;
  for (int i=tid;i<nw;i+=256){
    unsigned e = (wds[i] >> 7) & 0xFFu;
    c += (e >= 96u && e <= 160u) ? 1 : 0;
  }
  cnt[tid]=c; hist[tid]=0;
  __syncthreads();
  for (int s=128;s>0;s>>=1){
    if (tid<s) cnt[tid]+=cnt[tid+s];
    __syncthreads();
  }
  if (tid==0) flag[0] = (cnt[0]*2 > nw) ? 1 : 0;
  for (int i=tid;i<NB;i+=256) atomicAdd(&hist[lengths[i]&255],1);
  __syncthreads();
  {
    const int lane=tid&63, w=tid>>6;
    int v = hist[tid];
    int sum = v;
#pragma unroll
    for (int d=1; d<64; d<<=1){
      int o = __shfl_up(sum, d);
      if (lane >= d) sum += o;
    }
    if (lane==63) wsum[w]=sum;
    __syncthreads();
    int woff=0;
#pragma unroll
    for (int k=0;k<4;++k) if (k<w) woff+=wsum[k];
    base[tid] = woff + sum - v;
  }
  __syncthreads();
  for (int i=tid;i<NB;i+=256){
    int l=lengths[i]&255;
    int p=atomicAdd(&base[l],1);
    perm[p]=i;
  }
}

// ---------------- Fused DIEN (r13 structure) ----------------
__global__ __launch_bounds__(256,1)
void fused(const void* behavior, const void* target, const int* lengths,
           const void* Wih, const void* Whh, const void* bih, const void* bhh,
           const void* A1, const void* b1, const void* A2,
           const void* Wr, const void* br, const void* Wz, const void* bz,
           const void* Wn, const void* bn,
           const int* perm, const int* flag,
           unsigned short* hidden, float* out){
  const bool bf = flag[0]!=0;
  const int tid=threadIdx.x, lane=tid&63, w=tid>>6, l15=lane&15, q=lane>>4;
  const int g0 = blockIdx.x*8;
  const int xrow = ((l15>>2)<<1)|(l15&1);     // A-row -> batch (rowmap inverse, junk rows dup)

  __shared__ alignas(16) unsigned short x_s[2][CS][8][72];   // staged x chunks (ph1)
  __shared__ alignas(16) unsigned short h_lds[2][16][72];
  __shared__ alignas(16) unsigned short h_hist[16][8][72];   // 16-step ring, batch-indexed
  __shared__ alignas(16) unsigned short rh_lds[16][72];
  __shared__ float att_l[8][200];
  __shared__ float score_s[8][208];
  __shared__ float ct_s[8][64];
  __shared__ alignas(16) unsigned short tg_s[8][72];
  __shared__ float a2_s[64];
  __shared__ int rows8[8], lens8[8];

  if (tid<8){ int r=perm[g0+tid]; rows8[tid]=r; lens8[tid]=lengths[r]; }
  for (int i=tid;i<2*16*72;i+=256) ((unsigned short*)h_lds)[i]=0;
  for (int i=tid;i<16*72;i+=256)   ((unsigned short*)rh_lds)[i]=0;
  __syncthreads();

  int maxlen=1;
#pragma unroll
  for (int i=0;i<8;++i) maxlen = max(maxlen, lens8[i]);
  const int ml1 = maxlen-1;
  const int jc = w*16 + l15;

  const unsigned short* bp=(const unsigned short*)behavior;
  const float*          fp=(const float*)behavior;

  uint4 xr[10];                         // in-flight staging registers
  auto issue_g = [&](const unsigned short* src, int t0){
#pragma unroll
    for (int it=0; it<10; ++it){
      int i=it*256+tid, row=i/320, k=i-row*320;
      int t=min(t0+(k>>3), ml1), d0=(k&7)*8;
      xr[it] = *(const uint4*)(src + (long)rows8[row]*(SLEN*64) + t*64 + d0);
    }
  };
  auto write_s = [&](int b_){
#pragma unroll
    for (int it=0; it<10; ++it){
      int i=it*256+tid, row=i/320, k=i-row*320;
      *(uint4*)&x_s[b_][k>>3][row][(k&7)*8] = xr[it];
    }
  };
  auto f32_stage = [&](int b_, int t0){
#pragma unroll
    for (int it=0; it<10; ++it){
      int i=it*256+tid, row=i/320, k=i-row*320;
      int t=min(t0+(k>>3), ml1), d0=(k&7)*8;
      const float* s = fp + (long)rows8[row]*(SLEN*64) + t*64 + d0;
      f4 a=*(const f4*)s, b2=*(const f4*)(s+4);
      bf8s v;
#pragma unroll
      for (int j=0;j<4;++j){ v[j]=fb1(a[j]); v[4+j]=fb1(b2[j]); }
      *(bf8s*)&x_s[b_][k>>3][row][d0] = v;
    }
  };
  auto dump_window = [&](int tbase){
    int dt = tid>>5, row=(tid>>2)&7, cs=(tid&3)*16;
    int t = tbase+dt;
    if (t < lens8[row]){
      uint4 v0 = *(const uint4*)&h_hist[t&15][row][cs];
      uint4 v1 = *(const uint4*)&h_hist[t&15][row][cs+8];
      long o = ((long)rows8[row]*SLEN + t)*64 + cs;
      *(uint4*)&hidden[o]   = v0;
      *(uint4*)&hidden[o+8] = v1;
    }
  };

  // ================= Phase 1: interest-extraction GRU =================
  {
    bf8s wif[3][2], whf[3][2];
#pragma unroll
    for (int G=0;G<3;++G)
#pragma unroll
      for (int kf=0;kf<2;++kf){
        long off = (long)(G*64+jc)*64 + kf*32 + q*8;
        wif[G][kf] = loadfrag(Wih, off, bf);
        whf[G][kf] = loadfrag(Whh, off, bf);
      }
    const float Br  = ldf(bih,jc,bf)+ldf(bhh,jc,bf);
    const float Bz  = ldf(bih,64+jc,bf)+ldf(bhh,64+jc,bf);
    const float Bin = ldf(bih,128+jc,bf);
    const float Bhn = ldf(bhh,128+jc,bf);
    int Ln2[2];
#pragma unroll
    for (int i=0;i<2;++i) Ln2[i] = lens8[2*q+i];
    float hreg[2]={0.f,0.f};

    if (bf){ issue_g(bp,0); write_s(0); if (maxlen>CS) issue_g(bp,CS); }
    else   { f32_stage(0,0); }
    __syncthreads();

    int c=0;
    for (int t0=0; t0<maxlen; t0+=CS, ++c){
      const int tend = min(t0+CS, maxlen);
      for (int t=t0; t<tend; ++t){
        if ((t&7)==0 && t>=8) dump_window(t-8);
        const int tc = t-t0;
        bf8s xa0 = *(const bf8s*)&x_s[c&1][tc][xrow][q*8];
        bf8s xa1 = *(const bf8s*)&x_s[c&1][tc][xrow][32+q*8];
        bf8s ha0 = *(const bf8s*)&h_lds[t&1][l15][q*8];
        bf8s ha1 = *(const bf8s*)&h_lds[t&1][l15][32+q*8];

        f4 Tr  = {Br,Br,Br,Br};
        f4 Tz  = {Bz,Bz,Bz,Bz};
        f4 Txn = {Bin,Bin,Bin,Bin};
        f4 Thn = {Bhn,Bhn,Bhn,Bhn};
        Tr =MF(xa0,wif[0][0],Tr );  Tr =MF(xa1,wif[0][1],Tr );
        Tz =MF(xa0,wif[1][0],Tz );  Tz =MF(xa1,wif[1][1],Tz );
        Txn=MF(xa0,wif[2][0],Txn);  Txn=MF(xa1,wif[2][1],Txn);
        Tr =MF(ha0,whf[0][0],Tr );  Tr =MF(ha1,whf[0][1],Tr );
        Tz =MF(ha0,whf[1][0],Tz );  Tz =MF(ha1,whf[1][1],Tz );
        Thn=MF(ha0,whf[2][0],Thn); Thn=MF(ha1,whf[2][1],Thn);

        const int nb_=(t+1)&1;
#pragma unroll
        for (int i=0;i<2;++i){
          const int ar = 4*q+i;          // D-row / A-row (rowmap space)
          const int b_ = 2*q+i;          // batch slot
          float rg = sigm(Tr[i]);
          float zg = sigm(Tz[i]);
          float ng = tanh_(Txn[i] + rg*Thn[i]);
          float hold = hreg[i];
          float hnew = (1.f-zg)*ng + zg*hold;
          float hv = (t < Ln2[i]) ? hnew : hold;
          hreg[i] = hv;
          unsigned short hb16 = (unsigned short)fb1(hv);
          h_lds[nb_][ar][jc] = hb16;
          h_hist[t&15][b_][jc] = hb16;
        }
        sync_lds();
      }
      if (t0+CS < maxlen){
        if (bf){ write_s((c+1)&1); if (t0+2*CS < maxlen) issue_g(bp, t0+2*CS); }
        else   { f32_stage((c+1)&1, t0+CS); }
        sync_lds();
      }
    }
    dump_window((maxlen-1)&~7);
    asm volatile("s_waitcnt vmcnt(0)" ::: "memory");
  }
  __syncthreads();   // hidden complete & visible

  // ================= Phase 2: attention MLP + masked softmax =================
  for (int i=tid;i<8*64;i+=256){
    int r=i>>6, c2=i&63;
    tg_s[r][c2] = (unsigned short)fb1(ldf(target,(long)rows8[r]*64 + c2, bf));
  }
  if (tid<64) a2_s[tid]=ldf(A2,tid,bf);
  __syncthreads();

  {
    // ct via MFMA: D(a = w*16+4q+i, batch = l15) = A1h2 @ tg^T
    {
      bf8s a1c0 = loadfrag(A1,(long)(w*16+l15)*128 + 64 + q*8, bf);
      bf8s a1c1 = loadfrag(A1,(long)(w*16+l15)*128 + 96 + q*8, bf);
      bf8s tgf0 = *(const bf8s*)&tg_s[l15&7][q*8];
      bf8s tgf1 = *(const bf8s*)&tg_s[l15&7][32+q*8];
      f4 Dct={0.f,0.f,0.f,0.f};
      Dct=MF(a1c0,tgf0,Dct);
      Dct=MF(a1c1,tgf1,Dct);
      if (l15<8){
#pragma unroll
        for (int i=0;i<4;++i)
          ct_s[l15][w*16+4*q+i] = Dct[i] + ldf(b1,w*16+4*q+i,bf);
      }
    }
    bf8s a1f[4][2];
#pragma unroll
    for (int nt=0;nt<4;++nt)
#pragma unroll
      for (int kf=0;kf<2;++kf)
        a1f[nt][kf] = loadfrag(A1,(long)(nt*16+l15)*128 + kf*32 + q*8, bf);
    __syncthreads();   // ct_s complete

#pragma unroll
    for (int rr=0;rr<2;++rr){
      int r = 2*w+rr, lenr = lens8[r];
      int mtr = (lenr+15)>>4; if (mtr>13) mtr=13;
      for (int mt=0; mt<mtr; ++mt){
        const unsigned short* hp = &hidden[((long)rows8[r]*SLEN + mt*16+l15)*64 + q*8];
        bf8s h0 = *(const bf8s*)hp;
        bf8s h1 = *(const bf8s*)(hp+32);
        f4 acc[4];
#pragma unroll
        for (int nt=0;nt<4;++nt){
          f4 a={0.f,0.f,0.f,0.f};
          a=MF(h0,a1f[nt][0],a); a=MF(h1,a1f[nt][1],a); acc[nt]=a;
        }
#pragma unroll
        for (int i=0;i<4;++i){
          float s=0.f;
#pragma unroll
          for (int nt=0;nt<4;++nt){
            int au = nt*16 + l15;
            s += fmaxf(acc[nt][i]+ct_s[r][au],0.f)*a2_s[au];
          }
#pragma unroll
          for (int d=1; d<16; d<<=1) s += __shfl_xor(s,d);
          if (l15==0) score_s[r][mt*16+4*q+i] = s;
        }
      }
      int t0=lane, t1=64+lane, t2=128+lane, t3=192+lane;
      float v0=(t0<lenr)?score_s[r][t0]:-3e38f;
      float v1=(t1<lenr)?score_s[r][t1]:-3e38f;
      float v2=(t2<lenr)?score_s[r][t2]:-3e38f;
      float v3=(t3<lenr)?score_s[r][t3]:-3e38f;
      float m = fmaxf(fmaxf(v0,v1),fmaxf(v2,v3));
#pragma unroll
      for (int d=32;d>0;d>>=1) m = fmaxf(m,__shfl_xor(m,d));
      float e0=(t0<lenr)?__expf(v0-m):0.f;
      float e1=(t1<lenr)?__expf(v1-m):0.f;
      float e2=(t2<lenr)?__expf(v2-m):0.f;
      float e3=(t3<lenr)?__expf(v3-m):0.f;
      float S = e0+e1+e2+e3;
#pragma unroll
      for (int d=32;d>0;d>>=1) S += __shfl_xor(S,d);
      float Si = rcp_(S);
      att_l[r][t0] = e0*Si;
      att_l[r][t1] = e1*Si;
      if (t2<200) att_l[r][t2] = e2*Si;
      if (t3<200) att_l[r][t3] = e3*Si;
    }
  }
  __syncthreads();

  // ====== Phase 3: attentional GRU (direct global prefetch, rowmap) ======
  for (int i=tid;i<2*16*72;i+=256) ((unsigned short*)h_lds)[i]=0;

  bf8s wrf[2][2], wzf[2][2], wnf[2][2];     // [0]=hi part, [1]=h part
#pragma unroll
  for (int hh=0;hh<2;++hh)
#pragma unroll
    for (int kf=0;kf<2;++kf){
      long off = (long)jc*128 + hh*64 + kf*32 + q*8;
      wrf[hh][kf]=loadfrag(Wr,off,bf);
      wzf[hh][kf]=loadfrag(Wz,off,bf);
      wnf[hh][kf]=loadfrag(Wn,off,bf);
    }
  const float Brv=ldf(br,jc,bf), Bzv=ldf(bz,jc,bf), Bnv=ldf(bn,jc,bf);

  float h3[2]={0.f,0.f};
  const long hbase = (long)rows8[xrow]*(SLEN*64) + q*8;
  bf8s hb00,hb01,hb10,hb11;
  {
    long o1 = hbase + (long)min(1,ml1)*64;
    hb00=*(const bf8s*)(hidden+hbase); hb01=*(const bf8s*)(hidden+hbase+32);
    hb10=*(const bf8s*)(hidden+o1);    hb11=*(const bf8s*)(hidden+o1+32);
  }
  __syncthreads();   // h_lds zero visible

  for (int t=0;t<maxlen;++t){
    long po = hbase + (long)min(t+2,ml1)*64;
    bf8s pN0 = *(const bf8s*)(hidden+po);
    bf8s pN1 = *(const bf8s*)(hidden+po+32);

    bf8s ha0=*(const bf8s*)&h_lds[t&1][l15][q*8];
    bf8s ha1=*(const bf8s*)&h_lds[t&1][l15][32+q*8];

    f4 Tr = {Brv,Brv,Brv,Brv};
    f4 Tz = {Bzv,Bzv,Bzv,Bzv};
    f4 Tn = {Bnv,Bnv,Bnv,Bnv};
    Tr=MF(hb00,wrf[0][0],Tr); Tr=MF(hb01,wrf[0][1],Tr);
    Tz=MF(hb00,wzf[0][0],Tz); Tz=MF(hb01,wzf[0][1],Tz);
    Tn=MF(hb00,wnf[0][0],Tn); Tn=MF(hb01,wnf[0][1],Tn);
    Tr=MF(ha0, wrf[1][0],Tr); Tr=MF(ha1, wrf[1][1],Tr);
    Tz=MF(ha0, wzf[1][0],Tz); Tz=MF(ha1, wzf[1][1],Tz);

    float zs[2], hs[2];
#pragma unroll
    for (int i=0;i<2;++i){
      const int ar = 4*q+i;
      const int b_ = 2*q+i;
      float rg = sigm(Tr[i]);
      float ai = att_l[b_][t];
      float zg = sigm(Tz[i]) * ai;
      float hold = h3[i];
      zs[i]=zg; hs[i]=hold;
      rh_lds[ar][jc] = (unsigned short)fb1(rg*hold);
    }
    sync_lds();                            // rh visible

    bf8s ra0 = *(const bf8s*)&rh_lds[l15][q*8];
    bf8s ra1 = *(const bf8s*)&rh_lds[l15][32+q*8];
    Tn=MF(ra0,wnf[1][0],Tn); Tn=MF(ra1,wnf[1][1],Tn);

    const int nb_=(t+1)&1;
#pragma unroll
    for (int i=0;i<2;++i){
      const int ar = 4*q+i;
      float ng = tanh_(Tn[i]);
      float hnew = (zs[i]==0.f) ? hs[i] : hs[i] + zs[i]*(ng - hs[i]);
      h3[i] = hnew;
      h_lds[nb_][ar][jc] = (unsigned short)fb1(hnew);
    }
    hb00=hb10; hb01=hb11; hb10=pN0; hb11=pN1;
    sync_lds();                            // h visible
  }
#pragma unroll
  for (int i=0;i<2;++i)
    out[(long)rows8[2*q+i]*64 + jc] = h3[i];
}

extern "C" void kernel_launch(void* const* d_in, const int* in_sizes, int n_in,
                              void* d_out, int out_size, void* d_ws, size_t ws_size,
                              hipStream_t stream) {
  const void* behavior = d_in[0];
  const void* target   = d_in[1];
  const int*  lengths  = (const int*)d_in[2];
  const void* Wih = d_in[3];
  const void* Whh = d_in[4];
  const void* bih = d_in[5];
  const void* bhh = d_in[6];
  const void* A1  = d_in[7];
  const void* b1  = d_in[8];
  const void* A2  = d_in[9];
  const void* Wr  = d_in[10];
  const void* br  = d_in[11];
  const void* Wz  = d_in[12];
  const void* bz  = d_in[13];
  const void* Wn  = d_in[14];
  const void* bn  = d_in[15];

  int* flag = (int*)d_ws;
  unsigned short* hidden = (unsigned short*)((char*)d_ws + 256);
  int* perm = (int*)((char*)d_ws + 256 + (size_t)NB*SLEN*64*2);
  size_t needed = 256 + (size_t)NB*SLEN*64*2 + (size_t)NB*4;
  if (ws_size < needed) return;

  k0_prep<<<1, 256, 0, stream>>>((const unsigned int*)behavior, 4096, lengths, flag, perm);
  fused<<<NB/8, 256, 0, stream>>>(behavior, target, lengths,
                                  Wih, Whh, bih, bhh, A1, b1, A2,
                                  Wr, br, Wz, bz, Wn, bn,
                                  perm, flag, hidden, (float*)d_out);
}